// Round 2
// baseline (206.257 us; speedup 1.0000x reference)
//
#include <hip/hip_runtime.h>
#include <hip/hip_bf16.h>

#define BATCH 8
#define SEQ   2048
#define DIM   512
#define QB    64
#define KB    64
#define NT    512          // threads per block (8 waves)
#define NKV   (SEQ / KB)   // 32 KV tiles

typedef __attribute__((ext_vector_type(8))) short short8;
typedef __attribute__((ext_vector_type(4))) float f32x4;
typedef __attribute__((ext_vector_type(4))) unsigned short ushort4v;

__device__ __forceinline__ unsigned short f2bf(float f) {
    union { float f; unsigned u; } v; v.f = f;
    return (unsigned short)((v.u + 0x7FFFu + ((v.u >> 16) & 1u)) >> 16);
}

// score = X·X^T (no scaling), softmax, out = P·X
__global__ __launch_bounds__(NT, 2)
void attn_fwd(const float* __restrict__ X, float* __restrict__ O) {
    // XCD-aware: batch = bid & 7 so each XCD's 32 CUs share one 4MB KV stream in L2
    const int b   = blockIdx.x & 7;
    const int qt  = blockIdx.x >> 3;
    const int tid = threadIdx.x;
    const int lane = tid & 63;
    const int w    = tid >> 6;       // wave 0..7
    const int col  = lane & 15;
    const int kgrp = lane >> 4;      // 0..3

    // LDS: one copy of the KV tile (K==V==X), swizzled for conflict-free b128 row reads
    __shared__ unsigned short Klds[KB * DIM];       // [kv][d] bf16, idx-swizzle d ^= (kv&7)<<3
    __shared__ float Sbuf[QB][KB + 4];              // scores, padded
    __shared__ unsigned short Plds[QB * KB];        // [q][kv] bf16, idx-swizzle kv ^= (q&7)<<3
    __shared__ float m_s[QB], l_s[QB], fac_s[QB];

    const float* Xb = X + (size_t)b * SEQ * DIM;

    // ---- preload Q fragments: wave w computes S-strip qs = w>>1 (16 q rows)
    const int qs  = w >> 1;
    const int kc0 = (w & 1) * 2;
    short8 qfrag[16];
    {
        const int qrow = qt * QB + qs * 16 + col;
        const float* qp = Xb + (size_t)qrow * DIM;
        #pragma unroll
        for (int ks = 0; ks < 16; ++ks) {
            const int d0 = ks * 32 + kgrp * 8;
            float4 a = *(const float4*)(qp + d0);
            float4 c = *(const float4*)(qp + d0 + 4);
            short8 q8;
            q8[0] = f2bf(a.x); q8[1] = f2bf(a.y); q8[2] = f2bf(a.z); q8[3] = f2bf(a.w);
            q8[4] = f2bf(c.x); q8[5] = f2bf(c.y); q8[6] = f2bf(c.z); q8[7] = f2bf(c.w);
            qfrag[ks] = q8;
        }
    }

    if (tid < QB) { m_s[tid] = -INFINITY; l_s[tid] = 0.f; }

    // O accumulator: wave owns d-cols [w*64, (w+1)*64) for all 64 q rows
    f32x4 oacc[4][4];   // [q-subtile][d-subtile]
    #pragma unroll
    for (int i = 0; i < 4; ++i)
        #pragma unroll
        for (int j = 0; j < 4; ++j)
            oacc[i][j] = (f32x4){0.f, 0.f, 0.f, 0.f};

    for (int t = 0; t < NKV; ++t) {
        __syncthreads();   // (a) prev PV done reading Klds/Plds
        // ---- stage KV tile (fp32 -> bf16, swizzled)
        {
            const float* kp = Xb + (size_t)(t * KB) * DIM;
            #pragma unroll
            for (int it = 0; it < 16; ++it) {
                const int idx = it * NT + tid;
                const int kv  = idx >> 7;
                const int d0  = (idx & 127) * 4;
                float4 v = *(const float4*)(kp + kv * DIM + d0);
                ushort4v h;
                h[0] = f2bf(v.x); h[1] = f2bf(v.y); h[2] = f2bf(v.z); h[3] = f2bf(v.w);
                *(ushort4v*)&Klds[kv * DIM + (d0 ^ ((kv & 7) << 3))] = h;
            }
        }
        __syncthreads();   // (b) Klds ready

        // ---- QK^T: wave computes 2 tiles (qs, kc0) (qs, kc0+1), full D reduction
        #pragma unroll
        for (int i = 0; i < 2; ++i) {
            const int kc = kc0 + i;
            const int kvrow = kc * 16 + col;
            const unsigned short* kbase = &Klds[kvrow * DIM];
            const int sw = (kvrow & 7) << 3;
            f32x4 sacc = (f32x4){0.f, 0.f, 0.f, 0.f};
            #pragma unroll
            for (int ks = 0; ks < 16; ++ks) {
                const int d0 = (ks * 32 + kgrp * 8) ^ sw;
                short8 kfr = *(const short8*)(kbase + d0);
                sacc = __builtin_amdgcn_mfma_f32_16x16x32_bf16(qfrag[ks], kfr, sacc, 0, 0, 0);
            }
            // C layout: col=lane&15, row=(lane>>4)*4+r  [m89-verified]
            #pragma unroll
            for (int r = 0; r < 4; ++r)
                Sbuf[qs * 16 + kgrp * 4 + r][kc * 16 + col] = sacc[r];
        }
        __syncthreads();   // (c) Sbuf ready

        // ---- online softmax: 8 threads per row
        {
            const int r   = tid >> 3;
            const int sub = tid & 7;
            float4 sa = *(const float4*)&Sbuf[r][sub * 8];
            float4 sb = *(const float4*)&Sbuf[r][sub * 8 + 4];
            float mloc = fmaxf(fmaxf(fmaxf(sa.x, sa.y), fmaxf(sa.z, sa.w)),
                               fmaxf(fmaxf(sb.x, sb.y), fmaxf(sb.z, sb.w)));
            mloc = fmaxf(mloc, __shfl_xor(mloc, 1));
            mloc = fmaxf(mloc, __shfl_xor(mloc, 2));
            mloc = fmaxf(mloc, __shfl_xor(mloc, 4));
            const float mold = m_s[r];
            const float mnew = fmaxf(mold, mloc);
            const float fac  = __expf(mold - mnew);   // -inf on first tile -> 0
            float p0 = __expf(sa.x - mnew), p1 = __expf(sa.y - mnew);
            float p2 = __expf(sa.z - mnew), p3 = __expf(sa.w - mnew);
            float p4 = __expf(sb.x - mnew), p5 = __expf(sb.y - mnew);
            float p6 = __expf(sb.z - mnew), p7 = __expf(sb.w - mnew);
            float lsum = ((p0 + p1) + (p2 + p3)) + ((p4 + p5) + (p6 + p7));
            lsum += __shfl_xor(lsum, 1);
            lsum += __shfl_xor(lsum, 2);
            lsum += __shfl_xor(lsum, 4);
            short8 p8;
            p8[0] = f2bf(p0); p8[1] = f2bf(p1); p8[2] = f2bf(p2); p8[3] = f2bf(p3);
            p8[4] = f2bf(p4); p8[5] = f2bf(p5); p8[6] = f2bf(p6); p8[7] = f2bf(p7);
            *(short8*)&Plds[r * KB + ((sub * 8) ^ ((r & 7) << 3))] = p8;
            if (sub == 0) {
                m_s[r] = mnew;
                fac_s[r] = fac;
                l_s[r] = l_s[r] * fac + lsum;
            }
        }
        __syncthreads();   // (d) Plds / fac ready

        // ---- rescale O by fac, then PV accumulate
        #pragma unroll
        for (int q2 = 0; q2 < 4; ++q2) {
            #pragma unroll
            for (int r = 0; r < 4; ++r) {
                const float f = fac_s[q2 * 16 + kgrp * 4 + r];
                #pragma unroll
                for (int dt = 0; dt < 4; ++dt) oacc[q2][dt][r] *= f;
            }
        }
        #pragma unroll
        for (int kc2 = 0; kc2 < 2; ++kc2) {
            const int kvb = kc2 * 32 + kgrp * 8;
            short8 bfr[4];
            #pragma unroll
            for (int dt = 0; dt < 4; ++dt) {
                const int d = w * 64 + dt * 16 + col;
                short8 bv;
                #pragma unroll
                for (int j = 0; j < 8; ++j) {
                    const int kv = kvb + j;
                    bv[j] = (short)Klds[kv * DIM + (d ^ ((kv & 7) << 3))];
                }
                bfr[dt] = bv;
            }
            #pragma unroll
            for (int q2 = 0; q2 < 4; ++q2) {
                const int q = q2 * 16 + col;
                short8 pfr = *(const short8*)&Plds[q * KB + (kvb ^ ((q & 7) << 3))];
                #pragma unroll
                for (int dt = 0; dt < 4; ++dt)
                    oacc[q2][dt] = __builtin_amdgcn_mfma_f32_16x16x32_bf16(pfr, bfr[dt], oacc[q2][dt], 0, 0, 0);
            }
        }
    }

    // ---- epilogue: divide by l, store fp32
    #pragma unroll
    for (int q2 = 0; q2 < 4; ++q2) {
        #pragma unroll
        for (int r = 0; r < 4; ++r) {
            const int row = q2 * 16 + kgrp * 4 + r;
            const float inv = 1.f / l_s[row];
            float* op = O + ((size_t)b * SEQ + qt * QB + row) * DIM + w * 64 + col;
            #pragma unroll
            for (int dt = 0; dt < 4; ++dt)
                op[dt * 16] = oacc[q2][dt][r] * inv;
        }
    }
}

extern "C" void kernel_launch(void* const* d_in, const int* in_sizes, int n_in,
                              void* d_out, int out_size, void* d_ws, size_t ws_size,
                              hipStream_t stream) {
    const float* X = (const float*)d_in[0];
    float* Out = (float*)d_out;
    dim3 grid(BATCH * (SEQ / QB));   // 256 blocks = 1 per CU
    dim3 block(NT);
    hipLaunchKernelGGL(attn_fwd, grid, block, 0, stream, X, Out);
}